// Round 1
// baseline (337.581 us; speedup 1.0000x reference)
//
#include <hip/hip_runtime.h>

// BatchReLUTransformer: element-wise ReLU-relaxation bound propagation.
// Inputs (fp32): bounds (N,B,2), beta (N,B), last_bounds (N,B,2)
// Output (fp32): (N,B,2) = stack([out_l, out_u], axis=2)
// Memory-bound: ~448 MiB traffic per call -> target ~75 us at 6.3 TB/s.

__device__ __forceinline__ float2 relax_pair(float l, float u, float beta,
                                             float ll, float lu) {
    const bool ind1 = (u <= 0.0f);               // always inactive
    const bool ind2 = (l > 0.0f);                // always active
    const bool ind3 = (u > 0.0f) && (l < 0.0f);  // unstable

    const float diff  = ind3 ? (u - l) : 1.0f;   // safe divisor
    const float inv   = 1.0f / diff;
    const float lmbda = ind2 ? 1.0f : (ind3 ? u * inv : 0.0f);
    const float mu    = ind3 ? (-l * u * inv) : 0.0f;
    const float beff  = ind1 ? 0.0f : (ind2 ? 1.0f : beta);

    const float cur_l = ind2 ? l : 0.0f;
    const float cur_u = ind2 ? u : (ind3 ? u : 0.0f);

    const float new_l = fmaxf(beff, 0.0f) * ll + fminf(beff, 0.0f) * lu;
    const float new_u = fmaxf(lmbda, 0.0f) * lu + fminf(lmbda, 0.0f) * ll + mu;

    float2 r;
    r.x = fmaxf(cur_l, new_l);
    r.y = fminf(cur_u, new_u);
    return r;
}

// One thread handles 2 (l,u) pairs: float4 loads/stores on the interleaved
// arrays, float2 on beta. 16 B/lane coalesced.
__global__ __launch_bounds__(256) void batch_relu_transformer_kernel(
    const float4* __restrict__ bounds,      // (n_pairs/2) float4 = 2 pairs
    const float2* __restrict__ beta,        // (n_pairs/2) float2
    const float4* __restrict__ last_bounds,
    float4* __restrict__ out,
    long long n4) {
    long long i = (long long)blockIdx.x * blockDim.x + threadIdx.x;
    if (i >= n4) return;

    const float4 b  = bounds[i];
    const float4 lb = last_bounds[i];
    const float2 be = beta[i];

    const float2 p0 = relax_pair(b.x, b.y, be.x, lb.x, lb.y);
    const float2 p1 = relax_pair(b.z, b.w, be.y, lb.z, lb.w);

    float4 o;
    o.x = p0.x; o.y = p0.y;
    o.z = p1.x; o.w = p1.y;
    out[i] = o;
}

// Scalar tail for an odd final pair (not expected for N*B even, but safe).
__global__ void batch_relu_tail_kernel(const float* __restrict__ bounds,
                                       const float* __restrict__ beta,
                                       const float* __restrict__ last_bounds,
                                       float* __restrict__ out,
                                       long long pair_idx) {
    const float l  = bounds[2 * pair_idx];
    const float u  = bounds[2 * pair_idx + 1];
    const float ll = last_bounds[2 * pair_idx];
    const float lu = last_bounds[2 * pair_idx + 1];
    const float2 p = relax_pair(l, u, beta[pair_idx], ll, lu);
    out[2 * pair_idx]     = p.x;
    out[2 * pair_idx + 1] = p.y;
}

extern "C" void kernel_launch(void* const* d_in, const int* in_sizes, int n_in,
                              void* d_out, int out_size, void* d_ws, size_t ws_size,
                              hipStream_t stream) {
    const float* bounds      = (const float*)d_in[0];
    const float* beta        = (const float*)d_in[1];
    const float* last_bounds = (const float*)d_in[2];
    float* out = (float*)d_out;

    const long long n_pairs = (long long)in_sizes[1];  // beta element count = N*B
    const long long n4 = n_pairs / 2;                  // float4 work items

    const int block = 256;
    const long long grid = (n4 + block - 1) / block;
    batch_relu_transformer_kernel<<<(dim3)(unsigned)grid, block, 0, stream>>>(
        (const float4*)bounds, (const float2*)beta, (const float4*)last_bounds,
        (float4*)out, n4);

    if (n_pairs & 1) {
        batch_relu_tail_kernel<<<1, 1, 0, stream>>>(bounds, beta, last_bounds,
                                                    out, n_pairs - 1);
    }
}

// Round 2
// 328.327 us; speedup vs baseline: 1.0282x; 1.0282x over previous
//
#include <hip/hip_runtime.h>

// BatchReLUTransformer: element-wise ReLU-relaxation bound propagation.
// Inputs (fp32): bounds (N,B,2), beta (N,B), last_bounds (N,B,2)
// Output (fp32): (N,B,2) = stack([out_l, out_u], axis=2)
// Memory-bound streaming: 448 MiB logical traffic. R0 (1 float4/thread) hit
// 2.5 TB/s HBM / 120 us -> latency-limited. This round: unroll x4 per thread
// (12 loads in flight) + nontemporal hints on all streams (no reuse).

typedef float v4f __attribute__((ext_vector_type(4)));
typedef float v2f __attribute__((ext_vector_type(2)));

__device__ __forceinline__ v2f relax_pair(float l, float u, float beta,
                                          float ll, float lu) {
    const bool ind1 = (u <= 0.0f);               // always inactive
    const bool ind2 = (l > 0.0f);                // always active
    const bool ind3 = (u > 0.0f) && (l < 0.0f);  // unstable

    const float diff  = ind3 ? (u - l) : 1.0f;   // safe divisor
    const float inv   = 1.0f / diff;
    const float lmbda = ind2 ? 1.0f : (ind3 ? u * inv : 0.0f);
    const float mu    = ind3 ? (-l * u * inv) : 0.0f;
    const float beff  = ind1 ? 0.0f : (ind2 ? 1.0f : beta);

    const float cur_l = ind2 ? l : 0.0f;
    const float cur_u = ind2 ? u : (ind3 ? u : 0.0f);

    const float new_l = fmaxf(beff, 0.0f) * ll + fminf(beff, 0.0f) * lu;
    const float new_u = fmaxf(lmbda, 0.0f) * lu + fminf(lmbda, 0.0f) * ll + mu;

    v2f r;
    r.x = fmaxf(cur_l, new_l);
    r.y = fminf(cur_u, new_u);
    return r;
}

constexpr int UNROLL = 4;
constexpr int BLOCK  = 256;

// Each block covers a contiguous chunk of UNROLL*BLOCK float4-items; thread t
// handles items t + k*BLOCK (k=0..3) -> every access wave-coalesced, 12
// independent loads in flight per thread before first use.
__global__ __launch_bounds__(BLOCK) void batch_relu_transformer_kernel(
    const v4f* __restrict__ bounds,      // 2 (l,u) pairs per item
    const v2f* __restrict__ beta,
    const v4f* __restrict__ last_bounds,
    v4f* __restrict__ out,
    long long n4) {
    const long long base =
        (long long)blockIdx.x * (BLOCK * UNROLL) + threadIdx.x;

    long long idx[UNROLL];
    bool ok[UNROLL];
    v4f b[UNROLL], lb[UNROLL];
    v2f be[UNROLL];

#pragma unroll
    for (int k = 0; k < UNROLL; ++k) {
        idx[k] = base + (long long)k * BLOCK;
        ok[k] = (idx[k] < n4);
        if (ok[k]) {
            b[k]  = __builtin_nontemporal_load(&bounds[idx[k]]);
            lb[k] = __builtin_nontemporal_load(&last_bounds[idx[k]]);
            be[k] = __builtin_nontemporal_load(&beta[idx[k]]);
        }
    }

#pragma unroll
    for (int k = 0; k < UNROLL; ++k) {
        if (ok[k]) {
            const v2f p0 = relax_pair(b[k].x, b[k].y, be[k].x, lb[k].x, lb[k].y);
            const v2f p1 = relax_pair(b[k].z, b[k].w, be[k].y, lb[k].z, lb[k].w);
            v4f o;
            o.x = p0.x; o.y = p0.y; o.z = p1.x; o.w = p1.y;
            __builtin_nontemporal_store(o, &out[idx[k]]);
        }
    }
}

// Scalar tail for an odd final pair (n_pairs odd; not expected here, but safe).
__global__ void batch_relu_tail_kernel(const float* __restrict__ bounds,
                                       const float* __restrict__ beta,
                                       const float* __restrict__ last_bounds,
                                       float* __restrict__ out,
                                       long long pair_idx) {
    const float l  = bounds[2 * pair_idx];
    const float u  = bounds[2 * pair_idx + 1];
    const float ll = last_bounds[2 * pair_idx];
    const float lu = last_bounds[2 * pair_idx + 1];
    const v2f p = relax_pair(l, u, beta[pair_idx], ll, lu);
    out[2 * pair_idx]     = p.x;
    out[2 * pair_idx + 1] = p.y;
}

extern "C" void kernel_launch(void* const* d_in, const int* in_sizes, int n_in,
                              void* d_out, int out_size, void* d_ws, size_t ws_size,
                              hipStream_t stream) {
    const float* bounds      = (const float*)d_in[0];
    const float* beta        = (const float*)d_in[1];
    const float* last_bounds = (const float*)d_in[2];
    float* out = (float*)d_out;

    const long long n_pairs = (long long)in_sizes[1];  // beta count = N*B
    const long long n4 = n_pairs / 2;                  // float4 work items

    const long long per_block = (long long)BLOCK * UNROLL;
    const long long grid = (n4 + per_block - 1) / per_block;
    batch_relu_transformer_kernel<<<(dim3)(unsigned)grid, BLOCK, 0, stream>>>(
        (const v4f*)bounds, (const v2f*)beta, (const v4f*)last_bounds,
        (v4f*)out, n4);

    if (n_pairs & 1) {
        batch_relu_tail_kernel<<<1, 1, 0, stream>>>(bounds, beta, last_bounds,
                                                    out, n_pairs - 1);
    }
}